// Round 8
// baseline (158.964 us; speedup 1.0000x reference)
//
#include <hip/hip_runtime.h>
#include <math.h>

#define H 768
#define S 256
#define NB 4      // batch
#define TOPK 4
#define L 4
#define NH 8      // biaffine h-split chunks (96 h each)

// 2/ln2: tanh(x) = 1 - 2/(2^(C*x)+1)
#define CSCALE 2.8853900817779268f

typedef __bf16 bf16x8 __attribute__((ext_vector_type(8)));
typedef __bf16 bf16x4 __attribute__((ext_vector_type(4)));
typedef float floatx4 __attribute__((ext_vector_type(4)));

// Native-rate transcendentals. exp2f()/expf() without -ffast-math are OCML
// precise libcalls (~20 VALU ops) -- round 3's lesson.
__device__ __forceinline__ float exp2_native(float x) {
#if __has_builtin(__builtin_amdgcn_exp2f)
  return __builtin_amdgcn_exp2f(x);
#else
  float r; asm("v_exp_f32 %0, %1" : "=v"(r) : "v"(x)); return r;
#endif
}
__device__ __forceinline__ float rcp_native(float x) {
#if __has_builtin(__builtin_amdgcn_rcpf)
  return __builtin_amdgcn_rcpf(x);
#else
  float r; asm("v_rcp_f32 %0, %1" : "=v"(r) : "v"(x)); return r;
#endif
}

// tanh for the hidden epilogue (__expf is native-rate; passing since round 2)
__device__ __forceinline__ float fast_tanh(float x) {
  float cx = fminf(15.f, fmaxf(-15.f, x));
  float e = __expf(cx + cx);
  return __fdividef(e - 1.f, e + 1.f);
}

// ---------------------------------------------------------------------------
// Stage 1 (single GEMM, cvt fused into staging): C = pooled(1024x768) @ B^T,
// B rows 0..1535 = concat(Wa,Ua) (hi/lo 3-term split -> hij, CSCALE-scaled,
// bit-identical to round 7); 1536..2303 = dense dep half (+dense_b -> dpb);
// 2304..3071 = dense head half (-> hpb).
// Block 32m x 128n, 4 waves each 32x32 (2x2 of 16x16x32): per iter 8
// ds_read_b128 per 12 MFMA (proj) vs round 7's 6-per-6 -> less LDS-bound.
// Grid 32x24 = 768 blocks = 3/CU; blockIdx.y swizzled so proj(3x work) and
// dense blocks interleave for CU balance.
__global__ __launch_bounds__(256, 3) void mega_mfma(
    const float* __restrict__ pooled, const float* __restrict__ Wa_w,
    const float* __restrict__ Ua_w, const float* __restrict__ dense_w,
    const float* __restrict__ Wa_b, const float* __restrict__ Ua_b,
    const float* __restrict__ dense_b, float* __restrict__ hij,
    __bf16* __restrict__ dpb, __bf16* __restrict__ hpb) {
  __shared__ __align__(16) __bf16 Ahs[32][40];
  __shared__ __align__(16) __bf16 Als[32][40];
  __shared__ __align__(16) __bf16 Bhs[128][40];
  __shared__ __align__(16) __bf16 Bls[128][40];
  const int m0 = blockIdx.x * 32;
  const int g = blockIdx.y;                       // swizzle: even->proj, odd->dense
  const int ng = (g & 1) ? (12 + (g >> 1)) : (g >> 1);
  const int n0 = ng * 128;
  const bool isproj = (ng < 12);
  const int t = threadIdx.x;
  // A staging: 32 rows x 32 k fp32 -> hi/lo
  const int arow = t >> 3;                        // 0..31
  const int ka = (t & 7) * 4;
  const float* Arow = pooled + (size_t)(m0 + arow) * H;
  // B staging: 128 rows x 32 k; thread handles 16 floats of one row
  const int brow = t >> 1;                        // 0..127
  const int kb = (t & 1) * 16;
  const int ncol = n0 + brow;
  const float* Bsrc;
  if (ncol < H)            Bsrc = Wa_w + (size_t)ncol * H;
  else if (ncol < 2 * H)   Bsrc = Ua_w + (size_t)(ncol - H) * H;
  else if (ncol < 3 * H)   Bsrc = dense_w + (size_t)(ncol - 2 * H) * (2 * H);       // dep half
  else                     Bsrc = dense_w + (size_t)(ncol - 3 * H) * (2 * H) + H;   // head half
  const int lane = t & 63;
  const int wave = t >> 6;
  const int wn = wave * 32;
  const int fm = lane & 15;
  const int quad = lane >> 4;
  floatx4 acc[2][2] = {};

  for (int kc = 0; kc < H; kc += 32) {
    {  // A: float4 -> 4 hi + 4 lo (identical rounding to old cvt_kernel)
      float4 av = *(const float4*)&Arow[kc + ka];
      float f[4] = {av.x, av.y, av.z, av.w};
      union { __bf16 h[4]; ushort4 u; } ah, al;
#pragma unroll
      for (int k = 0; k < 4; ++k) {
        __bf16 hv = (__bf16)f[k];
        ah.h[k] = hv;
        al.h[k] = (__bf16)(f[k] - (float)hv);
      }
      *(ushort4*)&Ahs[arow][ka] = ah.u;
      *(ushort4*)&Als[arow][ka] = al.u;
    }
    {  // B: 4 float4 -> 16 hi (+ 16 lo for proj)
      float4 w0 = *(const float4*)&Bsrc[kc + kb];
      float4 w1 = *(const float4*)&Bsrc[kc + kb + 4];
      float4 w2 = *(const float4*)&Bsrc[kc + kb + 8];
      float4 w3 = *(const float4*)&Bsrc[kc + kb + 12];
      float f[16] = {w0.x, w0.y, w0.z, w0.w, w1.x, w1.y, w1.z, w1.w,
                     w2.x, w2.y, w2.z, w2.w, w3.x, w3.y, w3.z, w3.w};
      bf16x8 bh0, bh1;
#pragma unroll
      for (int k = 0; k < 8; ++k) { bh0[k] = (__bf16)f[k]; bh1[k] = (__bf16)f[k + 8]; }
      *(bf16x8*)&Bhs[brow][kb] = bh0;
      *(bf16x8*)&Bhs[brow][kb + 8] = bh1;
      if (isproj) {
        bf16x8 bl0, bl1;
#pragma unroll
        for (int k = 0; k < 8; ++k) {
          bl0[k] = (__bf16)(f[k] - (float)bh0[k]);
          bl1[k] = (__bf16)(f[k + 8] - (float)bh1[k]);
        }
        *(bf16x8*)&Bls[brow][kb] = bl0;
        *(bf16x8*)&Bls[brow][kb + 8] = bl1;
      }
    }
    __syncthreads();
    bf16x8 afh[2], bfh[2];
#pragma unroll
    for (int i = 0; i < 2; ++i) {
      afh[i] = *(const bf16x8*)&Ahs[i * 16 + fm][quad * 8];
      bfh[i] = *(const bf16x8*)&Bhs[wn + i * 16 + fm][quad * 8];
    }
    if (isproj) {
      bf16x8 afl[2], bfl[2];
#pragma unroll
      for (int i = 0; i < 2; ++i) {
        afl[i] = *(const bf16x8*)&Als[i * 16 + fm][quad * 8];
        bfl[i] = *(const bf16x8*)&Bls[wn + i * 16 + fm][quad * 8];
      }
#pragma unroll
      for (int i = 0; i < 2; ++i)
#pragma unroll
        for (int j = 0; j < 2; ++j) {  // per-acc order hh,hl,lh == round 7
          acc[i][j] = __builtin_amdgcn_mfma_f32_16x16x32_bf16(afh[i], bfh[j], acc[i][j], 0, 0, 0);
          acc[i][j] = __builtin_amdgcn_mfma_f32_16x16x32_bf16(afh[i], bfl[j], acc[i][j], 0, 0, 0);
          acc[i][j] = __builtin_amdgcn_mfma_f32_16x16x32_bf16(afl[i], bfh[j], acc[i][j], 0, 0, 0);
        }
    } else {
#pragma unroll
      for (int i = 0; i < 2; ++i)
#pragma unroll
        for (int j = 0; j < 2; ++j)
          acc[i][j] = __builtin_amdgcn_mfma_f32_16x16x32_bf16(afh[i], bfh[j], acc[i][j], 0, 0, 0);
    }
    __syncthreads();
  }
#pragma unroll
  for (int j = 0; j < 2; ++j) {
    const int col = n0 + wn + j * 16 + fm;
    if (col < 2 * H) {          // hij: CSCALE*(acc + proj bias)
      const float bias = (col < H) ? Wa_b[col] : Ua_b[col - H];
#pragma unroll
      for (int i = 0; i < 2; ++i)
#pragma unroll
        for (int rg = 0; rg < 4; ++rg) {
          const int row = m0 + i * 16 + quad * 4 + rg;
          hij[(size_t)row * 1536 + col] = CSCALE * (acc[i][j][rg] + bias);
        }
    } else if (col < 3 * H) {   // dp: + dense_b, bf16
      const int o = col - 2 * H;
      const float bias = dense_b[o];
#pragma unroll
      for (int i = 0; i < 2; ++i)
#pragma unroll
        for (int rg = 0; rg < 4; ++rg) {
          const int row = m0 + i * 16 + quad * 4 + rg;
          dpb[(size_t)row * H + o] = (__bf16)(acc[i][j][rg] + bias);
        }
    } else {                    // hp: raw, bf16
      const int o = col - 3 * H;
#pragma unroll
      for (int i = 0; i < 2; ++i)
#pragma unroll
        for (int rg = 0; rg < 4; ++rg) {
          const int row = m0 + i * 16 + quad * 4 + rg;
          hpb[(size_t)row * H + o] = (__bf16)acc[i][j][rg];
        }
    }
  }
}

// ---------------------------------------------------------------------------
// Stage 2: partial[ch][b,a,c] = Sva_ch + sum_{h in ch} (-2 va[h]) * rcp(2^(xi+xj)+1)
// 32x32 (a,c) tile, 2x2/thread, NH=8 chunks of 96 h -> 2048 blocks.
// Single-barrier double-buffered pipeline (validated rounds 5-7). Near the
// transcendental-pipe floor (~30 us busy) -- unchanged.
__global__ __launch_bounds__(256) void biaffine4(
    const float* __restrict__ hij, const float* __restrict__ va,
    float* __restrict__ partials) {
  __shared__ __align__(16) float his[2][16][34];
  __shared__ __align__(16) float hjs[2][16][34];
  __shared__ __align__(16) float vas2[96];
  __shared__ float svas;
  const int z = blockIdx.z;
  const int b = z >> 3;
  const int ch = z & 7;
  const int hc0 = ch * 96;
  const int a0 = blockIdx.y * 32;
  const int c0 = blockIdx.x * 32;
  const int t = threadIdx.x;
  if (t < 96) vas2[t] = -2.f * va[hc0 + t];
  __syncthreads();
  if (t < 64) {
    float s = vas2[t] + ((t < 32) ? vas2[t + 64] : 0.f);
#pragma unroll
    for (int off = 32; off > 0; off >>= 1) s += __shfl_xor(s, off);
    if (t == 0) svas = -0.5f * s;
  }
  const int lh = t & 15;
  const int lr = t >> 4;
  const int ca = (t & 15) * 2;
  const int aa = (t >> 4) * 2;
  const float* pi0b = hij + (size_t)(b * S + c0 + lr) * 1536 + hc0 + lh;
  const float* pi1b = hij + (size_t)(b * S + c0 + lr + 16) * 1536 + hc0 + lh;
  const float* pj0b = hij + (size_t)(b * S + a0 + lr) * 1536 + 768 + hc0 + lh;
  const float* pj1b = hij + (size_t)(b * S + a0 + lr + 16) * 1536 + 768 + hc0 + lh;
  float acc00 = 0.f, acc01 = 0.f, acc10 = 0.f, acc11 = 0.f;

  float pi0 = pi0b[0], pi1 = pi1b[0], pj0 = pj0b[0], pj1 = pj1b[0];
  for (int hr = 0; hr < 96; hr += 16) {
    const int bf = (hr >> 4) & 1;
    his[bf][lh][lr]      = pi0;
    his[bf][lh][lr + 16] = pi1;
    hjs[bf][lh][lr]      = pj0;
    hjs[bf][lh][lr + 16] = pj1;
    __syncthreads();
    if (hr + 16 < 96) {
      pi0 = pi0b[hr + 16]; pi1 = pi1b[hr + 16];
      pj0 = pj0b[hr + 16]; pj1 = pj1b[hr + 16];
    }
    float vreg[16];
    *(float4*)&vreg[0]  = *(const float4*)&vas2[hr + 0];
    *(float4*)&vreg[4]  = *(const float4*)&vas2[hr + 4];
    *(float4*)&vreg[8]  = *(const float4*)&vas2[hr + 8];
    *(float4*)&vreg[12] = *(const float4*)&vas2[hr + 12];
#pragma unroll
    for (int h = 0; h < 16; ++h) {
      float v = vreg[h];
      float2 xi = *(const float2*)&his[bf][h][ca];
      float2 xj = *(const float2*)&hjs[bf][h][aa];
      acc00 = fmaf(v, rcp_native(exp2_native(xi.x + xj.x) + 1.f), acc00);
      acc01 = fmaf(v, rcp_native(exp2_native(xi.y + xj.x) + 1.f), acc01);
      acc10 = fmaf(v, rcp_native(exp2_native(xi.x + xj.y) + 1.f), acc10);
      acc11 = fmaf(v, rcp_native(exp2_native(xi.y + xj.y) + 1.f), acc11);
    }
  }
  const float sv = svas;
  float* pout = partials + (size_t)ch * (NB * S * S);
  float2 r0 = {acc00 + sv, acc01 + sv};
  float2 r1 = {acc10 + sv, acc11 + sv};
  *(float2*)&pout[(b * S + a0 + aa) * S + c0 + ca]     = r0;
  *(float2*)&pout[(b * S + a0 + aa + 1) * S + c0 + ca] = r1;
}

// ---------------------------------------------------------------------------
// Stage 3 (topk + type-logits fused): combine 8 partials -> logits + top-4,
// then for each of the 4 candidates compute
//   out_type[row,k,l] = fc_b[l] + sum_o tanh(dp[row,o] + hp[b,cand,o]) * fc_w[l,o]
// One 64-thread block per (b,a) row. No idx round-trip, no extra kernel.
__global__ __launch_bounds__(64) void topk_final(
    const float* __restrict__ partials, const __bf16* __restrict__ dpb,
    const __bf16* __restrict__ hpb, const float* __restrict__ fc_w,
    const float* __restrict__ fc_b, float* __restrict__ logits,
    float* __restrict__ out_type) {
  const int row = blockIdx.x;  // b*S + a
  const int lane = threadIdx.x;
  const int P = NB * S * S;
  float v[4];
#pragma unroll
  for (int j = 0; j < 4; ++j) {
    int c = row * S + j * 64 + lane;
    float s0 = partials[c]         + partials[c + P];
    float s1 = partials[c + 2 * P] + partials[c + 3 * P];
    float s2 = partials[c + 4 * P] + partials[c + 5 * P];
    float s3 = partials[c + 6 * P] + partials[c + 7 * P];
    v[j] = (s0 + s1) + (s2 + s3);
    logits[c] = v[j];
  }
  int cand[TOPK];
#pragma unroll
  for (int k = 0; k < TOPK; ++k) {
    float bestv = v[0];
    int besti = lane;
#pragma unroll
    for (int j = 1; j < 4; ++j) {
      int c = j * 64 + lane;
      if (v[j] > bestv) { bestv = v[j]; besti = c; }
    }
#pragma unroll
    for (int off = 32; off > 0; off >>= 1) {
      float ov = __shfl_xor(bestv, off);
      int oi = __shfl_xor(besti, off);
      if (ov > bestv || (ov == bestv && oi < besti)) { bestv = ov; besti = oi; }
    }
    int mj = besti >> 6, ml = besti & 63;
#pragma unroll
    for (int j = 0; j < 4; ++j)
      if (lane == ml && j == mj) v[j] = -3.402823466e38f;
    cand[k] = besti;
  }
  // type logits for the 4 candidates
  const __bf16* dp = dpb + (size_t)row * H;
  const int brow0 = (row >> 8) << 8;  // b*S
#pragma unroll
  for (int k = 0; k < TOPK; ++k) {
    const __bf16* hp = hpb + (size_t)(brow0 + cand[k]) * H;
    float acc[L] = {};
#pragma unroll
    for (int j = 0; j < 3; ++j) {
      const int o = j * 256 + lane * 4;
      bf16x4 dv = *(const bf16x4*)&dp[o];
      bf16x4 hv = *(const bf16x4*)&hp[o];
      float hd[4];
#pragma unroll
      for (int c = 0; c < 4; ++c)
        hd[c] = fast_tanh((float)dv[c] + (float)hv[c]);
#pragma unroll
      for (int l = 0; l < L; ++l) {
        float4 w = *(const float4*)&fc_w[l * H + o];
        acc[l] = fmaf(hd[0], w.x, acc[l]);
        acc[l] = fmaf(hd[1], w.y, acc[l]);
        acc[l] = fmaf(hd[2], w.z, acc[l]);
        acc[l] = fmaf(hd[3], w.w, acc[l]);
      }
    }
#pragma unroll
    for (int l = 0; l < L; ++l)
#pragma unroll
      for (int off = 32; off > 0; off >>= 1) acc[l] += __shfl_xor(acc[l], off);
    if (lane == 0) {
#pragma unroll
      for (int l = 0; l < L; ++l)
        out_type[((size_t)row * TOPK + k) * L + l] = acc[l] + fc_b[l];
    }
  }
}

// ---------------------------------------------------------------------------
extern "C" void kernel_launch(void* const* d_in, const int* in_sizes, int n_in,
                              void* d_out, int out_size, void* d_ws, size_t ws_size,
                              hipStream_t stream) {
  const float* pooled  = (const float*)d_in[0];
  const float* Wa_w    = (const float*)d_in[1];
  const float* Wa_b    = (const float*)d_in[2];
  const float* Ua_w    = (const float*)d_in[3];
  const float* Ua_b    = (const float*)d_in[4];
  const float* va_w    = (const float*)d_in[5];
  const float* dense_w = (const float*)d_in[6];
  const float* dense_b = (const float*)d_in[7];
  const float* fc_w    = (const float*)d_in[8];
  const float* fc_b    = (const float*)d_in[9];

  float* logits   = (float*)d_out;            // (4,256,256)
  float* out_type = logits + NB * S * S;      // (4,256,4,4)

  // ws layout, 17.1 MB (< 19.7 MB known-good). No temporal aliasing needed:
  // mega writes hij/dpb/hpb; biaffine reads hij, writes partials; topk_final
  // reads partials/dpb/hpb.
  float*  hij      = (float*)d_ws;                   // [0, 1572864) f
  float*  partials = hij + 1572864;                  // [.., +2097152) f
  __bf16* dpb      = (__bf16*)(partials + 2097152);  // 786432 bf16
  __bf16* hpb      = dpb + 786432;                   // 786432 bf16

  mega_mfma<<<dim3(32, 24), 256, 0, stream>>>(pooled, Wa_w, Ua_w, dense_w,
                                              Wa_b, Ua_b, dense_b,
                                              hij, dpb, hpb);
  biaffine4<<<dim3(8, 8, NB * NH), 256, 0, stream>>>(hij, va_w, partials);
  topk_final<<<dim3(1024), 64, 0, stream>>>(partials, dpb, hpb, fc_w, fc_b,
                                            logits, out_type);
}

// Round 9
// 158.809 us; speedup vs baseline: 1.0010x; 1.0010x over previous
//
#include <hip/hip_runtime.h>
#include <math.h>

#define H 768
#define S 256
#define NB 4      // batch
#define TOPK 4
#define L 4
#define NH 8      // biaffine h-split chunks (96 h each)

// 2/ln2: tanh(x) = 1 - 2/(2^(C*x)+1)
#define CSCALE 2.8853900817779268f

typedef __bf16 bf16x8 __attribute__((ext_vector_type(8)));
typedef __bf16 bf16x4 __attribute__((ext_vector_type(4)));
typedef float floatx4 __attribute__((ext_vector_type(4)));

// Native-rate transcendentals. exp2f()/expf() without -ffast-math are OCML
// precise libcalls (~20 VALU ops) -- round 3's lesson.
__device__ __forceinline__ float exp2_native(float x) {
#if __has_builtin(__builtin_amdgcn_exp2f)
  return __builtin_amdgcn_exp2f(x);
#else
  float r; asm("v_exp_f32 %0, %1" : "=v"(r) : "v"(x)); return r;
#endif
}
__device__ __forceinline__ float rcp_native(float x) {
#if __has_builtin(__builtin_amdgcn_rcpf)
  return __builtin_amdgcn_rcpf(x);
#else
  float r; asm("v_rcp_f32 %0, %1" : "=v"(r) : "v"(x)); return r;
#endif
}

// tanh for the hidden epilogue (__expf is native-rate; passing since round 2)
__device__ __forceinline__ float fast_tanh(float x) {
  float cx = fminf(15.f, fmaxf(-15.f, x));
  float e = __expf(cx + cx);
  return __fdividef(e - 1.f, e + 1.f);
}

// ---------------------------------------------------------------------------
// Stage 1 (single GEMM, cvt fused, SOFTWARE-PIPELINED): C = pooled @ B^T,
// B rows 0..1535 = concat(Wa,Ua) (hi/lo 3-term split -> hij, CSCALE-scaled);
// 1536..2303 = dense dep half (+dense_b -> dpb); 2304..3071 = head half (hpb).
// Round 9: double-buffered LDS + single barrier per K-iter + next iter's
// global loads prefetched into registers right after the barrier (biaffine4's
// validated scheme) -- round 8 exposed ~700 cyc of L2/LLC latency per iter.
// Conversion arithmetic is byte-identical to round 8 -> outputs bit-identical.
__global__ __launch_bounds__(256) void mega_mfma(
    const float* __restrict__ pooled, const float* __restrict__ Wa_w,
    const float* __restrict__ Ua_w, const float* __restrict__ dense_w,
    const float* __restrict__ Wa_b, const float* __restrict__ Ua_b,
    const float* __restrict__ dense_b, float* __restrict__ hij,
    __bf16* __restrict__ dpb, __bf16* __restrict__ hpb) {
  __shared__ __align__(16) __bf16 Ahs[2][32][40];
  __shared__ __align__(16) __bf16 Als[2][32][40];
  __shared__ __align__(16) __bf16 Bhs[2][128][40];
  __shared__ __align__(16) __bf16 Bls[2][128][40];   // 51.2 KB total -> 3 blocks/CU
  const int m0 = blockIdx.x * 32;
  const int g = blockIdx.y;                       // swizzle: even->proj, odd->dense
  const int ng = (g & 1) ? (12 + (g >> 1)) : (g >> 1);
  const int n0 = ng * 128;
  const bool isproj = (ng < 12);
  const int t = threadIdx.x;
  // A staging: 32 rows x 32 k fp32 -> hi/lo
  const int arow = t >> 3;                        // 0..31
  const int ka = (t & 7) * 4;
  const float* Arow = pooled + (size_t)(m0 + arow) * H;
  // B staging: 128 rows x 32 k; thread handles 16 floats of one row
  const int brow = t >> 1;                        // 0..127
  const int kb = (t & 1) * 16;
  const int ncol = n0 + brow;
  const float* Bsrc;
  if (ncol < H)            Bsrc = Wa_w + (size_t)ncol * H;
  else if (ncol < 2 * H)   Bsrc = Ua_w + (size_t)(ncol - H) * H;
  else if (ncol < 3 * H)   Bsrc = dense_w + (size_t)(ncol - 2 * H) * (2 * H);       // dep half
  else                     Bsrc = dense_w + (size_t)(ncol - 3 * H) * (2 * H) + H;   // head half
  const int lane = t & 63;
  const int wave = t >> 6;
  const int wn = wave * 32;
  const int fm = lane & 15;
  const int quad = lane >> 4;
  floatx4 acc[2][2] = {};

  // prologue: prefetch kc = 0
  float4 av = *(const float4*)&Arow[ka];
  float4 w0 = *(const float4*)&Bsrc[kb];
  float4 w1 = *(const float4*)&Bsrc[kb + 4];
  float4 w2 = *(const float4*)&Bsrc[kb + 8];
  float4 w3 = *(const float4*)&Bsrc[kb + 12];

  for (int kc = 0; kc < H; kc += 32) {
    const int bfx = (kc >> 5) & 1;
    {  // A: float4 -> 4 hi + 4 lo (identical rounding to rounds 7-8)
      float f[4] = {av.x, av.y, av.z, av.w};
      union { __bf16 h[4]; ushort4 u; } ah, al;
#pragma unroll
      for (int k = 0; k < 4; ++k) {
        __bf16 hv = (__bf16)f[k];
        ah.h[k] = hv;
        al.h[k] = (__bf16)(f[k] - (float)hv);
      }
      *(ushort4*)&Ahs[bfx][arow][ka] = ah.u;
      *(ushort4*)&Als[bfx][arow][ka] = al.u;
    }
    {  // B: 4 float4 -> 16 hi (+ 16 lo for proj)
      float f[16] = {w0.x, w0.y, w0.z, w0.w, w1.x, w1.y, w1.z, w1.w,
                     w2.x, w2.y, w2.z, w2.w, w3.x, w3.y, w3.z, w3.w};
      bf16x8 bh0, bh1;
#pragma unroll
      for (int k = 0; k < 8; ++k) { bh0[k] = (__bf16)f[k]; bh1[k] = (__bf16)f[k + 8]; }
      *(bf16x8*)&Bhs[bfx][brow][kb] = bh0;
      *(bf16x8*)&Bhs[bfx][brow][kb + 8] = bh1;
      if (isproj) {
        bf16x8 bl0, bl1;
#pragma unroll
        for (int k = 0; k < 8; ++k) {
          bl0[k] = (__bf16)(f[k] - (float)bh0[k]);
          bl1[k] = (__bf16)(f[k + 8] - (float)bh1[k]);
        }
        *(bf16x8*)&Bls[bfx][brow][kb] = bl0;
        *(bf16x8*)&Bls[bfx][brow][kb + 8] = bl1;
      }
    }
    __syncthreads();  // single barrier; buf^1 writers are >=1 full iter behind
    if (kc + 32 < H) {  // prefetch next chunk -- in flight during MFMA below
      av = *(const float4*)&Arow[kc + 32 + ka];
      w0 = *(const float4*)&Bsrc[kc + 32 + kb];
      w1 = *(const float4*)&Bsrc[kc + 32 + kb + 4];
      w2 = *(const float4*)&Bsrc[kc + 32 + kb + 8];
      w3 = *(const float4*)&Bsrc[kc + 32 + kb + 12];
    }
    bf16x8 afh[2], bfh[2];
#pragma unroll
    for (int i = 0; i < 2; ++i) {
      afh[i] = *(const bf16x8*)&Ahs[bfx][i * 16 + fm][quad * 8];
      bfh[i] = *(const bf16x8*)&Bhs[bfx][wn + i * 16 + fm][quad * 8];
    }
    if (isproj) {
      bf16x8 afl[2], bfl[2];
#pragma unroll
      for (int i = 0; i < 2; ++i) {
        afl[i] = *(const bf16x8*)&Als[bfx][i * 16 + fm][quad * 8];
        bfl[i] = *(const bf16x8*)&Bls[bfx][wn + i * 16 + fm][quad * 8];
      }
#pragma unroll
      for (int i = 0; i < 2; ++i)
#pragma unroll
        for (int j = 0; j < 2; ++j) {  // per-acc order hh,hl,lh == rounds 7-8
          acc[i][j] = __builtin_amdgcn_mfma_f32_16x16x32_bf16(afh[i], bfh[j], acc[i][j], 0, 0, 0);
          acc[i][j] = __builtin_amdgcn_mfma_f32_16x16x32_bf16(afh[i], bfl[j], acc[i][j], 0, 0, 0);
          acc[i][j] = __builtin_amdgcn_mfma_f32_16x16x32_bf16(afl[i], bfh[j], acc[i][j], 0, 0, 0);
        }
    } else {
#pragma unroll
      for (int i = 0; i < 2; ++i)
#pragma unroll
        for (int j = 0; j < 2; ++j)
          acc[i][j] = __builtin_amdgcn_mfma_f32_16x16x32_bf16(afh[i], bfh[j], acc[i][j], 0, 0, 0);
    }
  }
#pragma unroll
  for (int j = 0; j < 2; ++j) {
    const int col = n0 + wn + j * 16 + fm;
    if (col < 2 * H) {          // hij: CSCALE*(acc + proj bias)
      const float bias = (col < H) ? Wa_b[col] : Ua_b[col - H];
#pragma unroll
      for (int i = 0; i < 2; ++i)
#pragma unroll
        for (int rg = 0; rg < 4; ++rg) {
          const int row = m0 + i * 16 + quad * 4 + rg;
          hij[(size_t)row * 1536 + col] = CSCALE * (acc[i][j][rg] + bias);
        }
    } else if (col < 3 * H) {   // dp: + dense_b, bf16
      const int o = col - 2 * H;
      const float bias = dense_b[o];
#pragma unroll
      for (int i = 0; i < 2; ++i)
#pragma unroll
        for (int rg = 0; rg < 4; ++rg) {
          const int row = m0 + i * 16 + quad * 4 + rg;
          dpb[(size_t)row * H + o] = (__bf16)(acc[i][j][rg] + bias);
        }
    } else {                    // hp: raw, bf16
      const int o = col - 3 * H;
#pragma unroll
      for (int i = 0; i < 2; ++i)
#pragma unroll
        for (int rg = 0; rg < 4; ++rg) {
          const int row = m0 + i * 16 + quad * 4 + rg;
          hpb[(size_t)row * H + o] = (__bf16)acc[i][j][rg];
        }
    }
  }
}

// ---------------------------------------------------------------------------
// Stage 2: partial[ch][b,a,c] = Sva_ch + sum_{h in ch} (-2 va[h]) * rcp(2^(xi+xj)+1)
// AT ROOFLINE: 36.6 cyc/wave-elem-group vs 38-cyc transcendental-pipe model
// (v_exp/v_rcp ~16 cyc/wave64); NH and occupancy changes measured neutral.
__global__ __launch_bounds__(256) void biaffine4(
    const float* __restrict__ hij, const float* __restrict__ va,
    float* __restrict__ partials) {
  __shared__ __align__(16) float his[2][16][34];
  __shared__ __align__(16) float hjs[2][16][34];
  __shared__ __align__(16) float vas2[96];
  __shared__ float svas;
  const int z = blockIdx.z;
  const int b = z >> 3;
  const int ch = z & 7;
  const int hc0 = ch * 96;
  const int a0 = blockIdx.y * 32;
  const int c0 = blockIdx.x * 32;
  const int t = threadIdx.x;
  if (t < 96) vas2[t] = -2.f * va[hc0 + t];
  __syncthreads();
  if (t < 64) {
    float s = vas2[t] + ((t < 32) ? vas2[t + 64] : 0.f);
#pragma unroll
    for (int off = 32; off > 0; off >>= 1) s += __shfl_xor(s, off);
    if (t == 0) svas = -0.5f * s;
  }
  const int lh = t & 15;
  const int lr = t >> 4;
  const int ca = (t & 15) * 2;
  const int aa = (t >> 4) * 2;
  const float* pi0b = hij + (size_t)(b * S + c0 + lr) * 1536 + hc0 + lh;
  const float* pi1b = hij + (size_t)(b * S + c0 + lr + 16) * 1536 + hc0 + lh;
  const float* pj0b = hij + (size_t)(b * S + a0 + lr) * 1536 + 768 + hc0 + lh;
  const float* pj1b = hij + (size_t)(b * S + a0 + lr + 16) * 1536 + 768 + hc0 + lh;
  float acc00 = 0.f, acc01 = 0.f, acc10 = 0.f, acc11 = 0.f;

  float pi0 = pi0b[0], pi1 = pi1b[0], pj0 = pj0b[0], pj1 = pj1b[0];
  for (int hr = 0; hr < 96; hr += 16) {
    const int bf = (hr >> 4) & 1;
    his[bf][lh][lr]      = pi0;
    his[bf][lh][lr + 16] = pi1;
    hjs[bf][lh][lr]      = pj0;
    hjs[bf][lh][lr + 16] = pj1;
    __syncthreads();
    if (hr + 16 < 96) {
      pi0 = pi0b[hr + 16]; pi1 = pi1b[hr + 16];
      pj0 = pj0b[hr + 16]; pj1 = pj1b[hr + 16];
    }
    float vreg[16];
    *(float4*)&vreg[0]  = *(const float4*)&vas2[hr + 0];
    *(float4*)&vreg[4]  = *(const float4*)&vas2[hr + 4];
    *(float4*)&vreg[8]  = *(const float4*)&vas2[hr + 8];
    *(float4*)&vreg[12] = *(const float4*)&vas2[hr + 12];
#pragma unroll
    for (int h = 0; h < 16; ++h) {
      float v = vreg[h];
      float2 xi = *(const float2*)&his[bf][h][ca];
      float2 xj = *(const float2*)&hjs[bf][h][aa];
      acc00 = fmaf(v, rcp_native(exp2_native(xi.x + xj.x) + 1.f), acc00);
      acc01 = fmaf(v, rcp_native(exp2_native(xi.y + xj.x) + 1.f), acc01);
      acc10 = fmaf(v, rcp_native(exp2_native(xi.x + xj.y) + 1.f), acc10);
      acc11 = fmaf(v, rcp_native(exp2_native(xi.y + xj.y) + 1.f), acc11);
    }
  }
  const float sv = svas;
  float* pout = partials + (size_t)ch * (NB * S * S);
  float2 r0 = {acc00 + sv, acc01 + sv};
  float2 r1 = {acc10 + sv, acc11 + sv};
  *(float2*)&pout[(b * S + a0 + aa) * S + c0 + ca]     = r0;
  *(float2*)&pout[(b * S + a0 + aa + 1) * S + c0 + ca] = r1;
}

// ---------------------------------------------------------------------------
// Stage 3 (topk + type-logits fused): combine 8 partials -> logits + top-4,
// then out_type[row,k,l] = fc_b[l] + sum_o tanh(dp[row,o]+hp[b,cand,o])*fc_w[l,o]
__global__ __launch_bounds__(64) void topk_final(
    const float* __restrict__ partials, const __bf16* __restrict__ dpb,
    const __bf16* __restrict__ hpb, const float* __restrict__ fc_w,
    const float* __restrict__ fc_b, float* __restrict__ logits,
    float* __restrict__ out_type) {
  const int row = blockIdx.x;  // b*S + a
  const int lane = threadIdx.x;
  const int P = NB * S * S;
  float v[4];
#pragma unroll
  for (int j = 0; j < 4; ++j) {
    int c = row * S + j * 64 + lane;
    float s0 = partials[c]         + partials[c + P];
    float s1 = partials[c + 2 * P] + partials[c + 3 * P];
    float s2 = partials[c + 4 * P] + partials[c + 5 * P];
    float s3 = partials[c + 6 * P] + partials[c + 7 * P];
    v[j] = (s0 + s1) + (s2 + s3);
    logits[c] = v[j];
  }
  int cand[TOPK];
#pragma unroll
  for (int k = 0; k < TOPK; ++k) {
    float bestv = v[0];
    int besti = lane;
#pragma unroll
    for (int j = 1; j < 4; ++j) {
      int c = j * 64 + lane;
      if (v[j] > bestv) { bestv = v[j]; besti = c; }
    }
#pragma unroll
    for (int off = 32; off > 0; off >>= 1) {
      float ov = __shfl_xor(bestv, off);
      int oi = __shfl_xor(besti, off);
      if (ov > bestv || (ov == bestv && oi < besti)) { bestv = ov; besti = oi; }
    }
    int mj = besti >> 6, ml = besti & 63;
#pragma unroll
    for (int j = 0; j < 4; ++j)
      if (lane == ml && j == mj) v[j] = -3.402823466e38f;
    cand[k] = besti;
  }
  // type logits for the 4 candidates
  const __bf16* dp = dpb + (size_t)row * H;
  const int brow0 = (row >> 8) << 8;  // b*S
#pragma unroll
  for (int k = 0; k < TOPK; ++k) {
    const __bf16* hp = hpb + (size_t)(brow0 + cand[k]) * H;
    float acc[L] = {};
#pragma unroll
    for (int j = 0; j < 3; ++j) {
      const int o = j * 256 + lane * 4;
      bf16x4 dv = *(const bf16x4*)&dp[o];
      bf16x4 hv = *(const bf16x4*)&hp[o];
      float hd[4];
#pragma unroll
      for (int c = 0; c < 4; ++c)
        hd[c] = fast_tanh((float)dv[c] + (float)hv[c]);
#pragma unroll
      for (int l = 0; l < L; ++l) {
        float4 w = *(const float4*)&fc_w[l * H + o];
        acc[l] = fmaf(hd[0], w.x, acc[l]);
        acc[l] = fmaf(hd[1], w.y, acc[l]);
        acc[l] = fmaf(hd[2], w.z, acc[l]);
        acc[l] = fmaf(hd[3], w.w, acc[l]);
      }
    }
#pragma unroll
    for (int l = 0; l < L; ++l)
#pragma unroll
      for (int off = 32; off > 0; off >>= 1) acc[l] += __shfl_xor(acc[l], off);
    if (lane == 0) {
#pragma unroll
      for (int l = 0; l < L; ++l)
        out_type[((size_t)row * TOPK + k) * L + l] = acc[l] + fc_b[l];
    }
  }
}

// ---------------------------------------------------------------------------
extern "C" void kernel_launch(void* const* d_in, const int* in_sizes, int n_in,
                              void* d_out, int out_size, void* d_ws, size_t ws_size,
                              hipStream_t stream) {
  const float* pooled  = (const float*)d_in[0];
  const float* Wa_w    = (const float*)d_in[1];
  const float* Wa_b    = (const float*)d_in[2];
  const float* Ua_w    = (const float*)d_in[3];
  const float* Ua_b    = (const float*)d_in[4];
  const float* va_w    = (const float*)d_in[5];
  const float* dense_w = (const float*)d_in[6];
  const float* dense_b = (const float*)d_in[7];
  const float* fc_w    = (const float*)d_in[8];
  const float* fc_b    = (const float*)d_in[9];

  float* logits   = (float*)d_out;            // (4,256,256)
  float* out_type = logits + NB * S * S;      // (4,256,4,4)

  // ws layout, 17.1 MB (< 22.8 MB known-good). mega writes hij/dpb/hpb;
  // biaffine reads hij, writes partials; topk_final reads partials/dpb/hpb.
  float*  hij      = (float*)d_ws;                   // [0, 1572864) f
  float*  partials = hij + 1572864;                  // [.., +2097152) f
  __bf16* dpb      = (__bf16*)(partials + 2097152);  // 786432 bf16
  __bf16* hpb      = dpb + 786432;                   // 786432 bf16

  mega_mfma<<<dim3(32, 24), 256, 0, stream>>>(pooled, Wa_w, Ua_w, dense_w,
                                              Wa_b, Ua_b, dense_b,
                                              hij, dpb, hpb);
  biaffine4<<<dim3(8, 8, NB * NH), 256, 0, stream>>>(hij, va_w, partials);
  topk_final<<<dim3(1024), 64, 0, stream>>>(partials, dpb, hpb, fc_w, fc_b,
                                            logits, out_type);
}